// Round 16
// baseline (50.236 us; speedup 1.0000x reference)
//
#include <hip/hip_runtime.h>
#include <hip/hip_bf16.h>

// Quantized int8 3x3 conv via implicit-im2col MFMA (mfma_i32_16x16x64_i8).
// out = 1e-4*dot + asumf[px] + bconst[co]
//
// Round-16 structure (R15 minus sched_barriers):
//   - NO sched_barrier(0): the fully-unrolled 18-kstep body is one schedulable
//     region -> compiler can overlap kstep k+1 ds_reads with kstep k MFMAs
//     (the SBs were measured-neutral-to-harmful; triple-buffer protects A)
//   - A: L2->regs, 2 frags/kstep, named TRIPLE buffer wa/wb/wc (distance 2)
//   - wave tile 32co x 112px (m2 x p7), block 128co x 112px, 4 waves
//   - B: 7 ds_read_b128/kstep split 4+3; setprio(1) around MFMA clusters
//   - prep = fused repack_in + repack_w; asum folded in conv prologue
//   - input slab ip2[n][h][q8][w64][16B] staged dense once; no loop barriers
//   - chunked XCD swizzle 1728 = 8 x 216; launch_bounds(256,4)

#define N_B   32
#define C_IN  128
#define H_IN  56
#define W_IN  56
#define C_OUT 256
#define H_OUT 54
#define W_OUT 54
#define K_TOT 1152
#define NPX   (N_B * H_OUT * W_OUT)   // 93312
#define PXROW (H_OUT * W_OUT)         // 2916

using i32x4  = __attribute__((ext_vector_type(4))) int;

static __device__ __forceinline__ int dot4(int a, int b, int c) {
#if __has_builtin(__builtin_amdgcn_sdot4)
  return __builtin_amdgcn_sdot4(a, b, c, false);
#else
  signed char a0 = (signed char)a, a1 = (signed char)(a >> 8),
              a2 = (signed char)(a >> 16), a3 = (signed char)(a >> 24);
  signed char b0 = (signed char)b, b1 = (signed char)(b >> 8),
              b2 = (signed char)(b >> 16), b3 = (signed char)(b >> 24);
  return c + a0 * b0 + a1 * b1 + a2 * b2 + a3 * b3;
#endif
}

__device__ __forceinline__ void gload16(const void* g, void* l) {
  __builtin_amdgcn_global_load_lds(
      (const __attribute__((address_space(1))) void*)g,
      (__attribute__((address_space(3))) void*)l, 16, 0, 0);
}

// ---------------- fused prep:
//   blocks [0,1792): repack_in  NCHW(int32) -> ip2[n][h][q8][w64][16B] + rs
//   blocks [1792,1920): repack_w (2 co per block) -> wq3 + bconst
__global__ void prep(const int* __restrict__ in, const int* __restrict__ wsrc,
                     const float* __restrict__ bias,
                     signed char* __restrict__ ip2, int* __restrict__ rs,
                     signed char* __restrict__ wq3, float* __restrict__ bconst) {
  const int bid = blockIdx.x, tid = threadIdx.x;
  __shared__ int t32[C_IN * W_IN];   // 28KB (repack_in) / red[256] aliased
  __shared__ int rsum[W_IN];

  if (bid < 1792) {
    const int h = bid % 56, n = bid / 56;
    if (tid < W_IN) rsum[tid] = 0;
    int ci = tid >> 1, hf = tid & 1;
    const int* s = in + ((size_t)n * C_IN + ci) * (H_IN * W_IN) + h * W_IN + hf * 28;
    int* d = &t32[ci * W_IN + hf * 28];
#pragma unroll
    for (int k = 0; k < 7; ++k)
      *(int4*)(d + k * 4) = *(const int4*)(s + k * 4);
    __syncthreads();

    signed char* dst = ip2 + ((size_t)n * H_IN + h) * 8192;
#pragma unroll
    for (int jj = 0; jj < 2; ++jj) {
      int j = jj * 256 + tid;          // 0..511: q = j>>6, w = j&63
      int q = j >> 6, w = j & 63;
      if (w < W_IN) {
        int b[4], srow = 0;
#pragma unroll
        for (int qq = 0; qq < 4; ++qq) {
          int x0 = t32[(q * 16 + qq * 4 + 0) * W_IN + w];
          int x1 = t32[(q * 16 + qq * 4 + 1) * W_IN + w];
          int x2 = t32[(q * 16 + qq * 4 + 2) * W_IN + w];
          int x3 = t32[(q * 16 + qq * 4 + 3) * W_IN + w];
          b[qq] = (x0 & 255) | ((x1 & 255) << 8) | ((x2 & 255) << 16) | ((x3 & 255) << 24);
          srow = dot4(b[qq], 0x01010101, srow);
        }
        *(int4*)(dst + (size_t)q * 1024 + w * 16) = *(int4*)b;
        atomicAdd(&rsum[w], srow);
      }
    }
    __syncthreads();
    if (tid < W_IN) rs[((size_t)n * H_IN + h) * W_IN + tid] = rsum[tid];
  } else {
    int* red = t32;
    const int co = (bid - 1792) * 2 + (tid >> 7);
    const int ci = tid & 127;
    const int* wrow = wsrc + (size_t)co * K_TOT + (size_t)ci * 9;
    int s = 0;
    int kk = ci >> 5, hh = (ci >> 4) & 1, b = ci & 15;
    size_t base = (size_t)kk * 8192 + hh * 4096 + co * 16 + b;
#pragma unroll
    for (int t = 0; t < 9; ++t) {
      int v = wrow[t];
      s += v;
      wq3[(size_t)t * 32768 + base] = (signed char)v;
    }
    red[tid] = s;
    __syncthreads();
    for (int off = 64; off > 0; off >>= 1) {
      if (ci < off) red[tid] += red[tid + off];
      __syncthreads();
    }
    if (ci == 0) {
      int wsum = red[tid];
      float r = rintf(bias[co] / 0.0001f);                 // round half-even
      r = fminf(fmaxf(r, -2147483648.0f), 2147483647.0f);  // clamp to i32 range
      bconst[co] = 1e-4f * (float)(-7 * wsum + 24192) + r * 0.0001f;
    }
  }
}

__device__ __forceinline__ int mklb(int pf, int pxl, int c16) {
  int j = pf * 16 + pxl;
  int jc = j > 107 ? 107 : j;
  int dy = (jc >= 54) ? 1 : 0;
  return c16 * 4096 + dy * 1024 + (jc - dy * 54) * 16;
}

// ---------------- main MFMA conv (asum folded in)
__launch_bounds__(256, 4)
__global__ void conv_mfma(const signed char* __restrict__ ip2,
                          const signed char* __restrict__ wq3,
                          const int* __restrict__ rs,
                          const float* __restrict__ bconst,
                          float* __restrict__ out) {
  __shared__ signed char lds[32768];   // [plane i(8)=ci/16][row(4)][w(64)][16B]
  __shared__ float asf_lds[112];
  const int tid = threadIdx.x, w = tid >> 6, l = tid & 63;
  const int c16 = l >> 4, pxl = l & 15;

  // chunked XCD swizzle: 1728 = 8 xcd * 216
  const int b0 = blockIdx.x;
  const int wg = (b0 & 7) * 216 + (b0 >> 3);
  const int cq = wg & 1;               // co half 0..1
  const int nr = wg >> 1;              // n*27 + rp
  const int n  = nr / 27;
  const int rp = nr - n * 27;
  const int y0 = rp * 2;

  // ---- stage slab DENSE (4 input rows, 32KB)
  const signed char* ipn = ip2 + ((size_t)n * H_IN + y0) * 8192;
  {
    const int r = tid >> 6;
    const int off = (tid & 63) * 16;
    const signed char* src = ipn + (size_t)r * 8192 + off;
#pragma unroll
    for (int i = 0; i < 8; ++i)
      gload16(src + (size_t)i * 1024, &lds[i * 4096 + tid * 16]);
  }

  // ---- inline asum: asf_lds[j] = -3e-4 * sum of 3x3 rs window (L2-hot)
  if (tid < 108) {
    int dy = (tid >= 54) ? 1 : 0;
    int x  = tid - dy * 54;
    const int* rp_ = rs + ((size_t)n * H_IN + y0 + dy) * W_IN + x;
    int s = 0;
#pragma unroll
    for (int kh = 0; kh < 3; ++kh)
      s += rp_[kh * W_IN + 0] + rp_[kh * W_IN + 1] + rp_[kh * W_IN + 2];
    asf_lds[tid] = -3e-4f * (float)s;
  }

  // ---- per-lane B pixel bases: pf covers px j = pf*16 + pxl (112 px tile)
  const int lb0 = mklb(0, pxl, c16), lb1 = mklb(1, pxl, c16), lb2 = mklb(2, pxl, c16),
            lb3 = mklb(3, pxl, c16), lb4 = mklb(4, pxl, c16), lb5 = mklb(5, pxl, c16),
            lb6 = mklb(6, pxl, c16);

  // ---- A source: co = cq*128 + w*32 + m*16 + pxl, k-chunk c16
  const signed char* awq = wq3 + (size_t)c16 * 4096 +
                           (size_t)(cq * 128 + w * 32 + pxl) * 16;

  i32x4 a0_0 = {0,0,0,0}, a0_1 = {0,0,0,0}, a0_2 = {0,0,0,0}, a0_3 = {0,0,0,0},
        a0_4 = {0,0,0,0}, a0_5 = {0,0,0,0}, a0_6 = {0,0,0,0};
  i32x4 a1_0 = {0,0,0,0}, a1_1 = {0,0,0,0}, a1_2 = {0,0,0,0}, a1_3 = {0,0,0,0},
        a1_4 = {0,0,0,0}, a1_5 = {0,0,0,0}, a1_6 = {0,0,0,0};
  i32x4 wa0, wa1, wb0, wb1, wc0, wc1;

#define LDW(P, t)                                                              \
  P##0 = *(const i32x4*)(awq + (size_t)(t) * 16384);                           \
  P##1 = *(const i32x4*)(awq + (size_t)(t) * 16384 + 256);

  LDW(wa, 0);
  LDW(wb, 1);
  __syncthreads();   // slab + asf staged — the ONLY barrier

  // A triple buffer: kstep ks uses buf[ks%3], prefetches ks+2 into buf[(ks+2)%3]
  // NO sched_barriers: compiler free to software-pipeline across ksteps.
#define KSTEP(ks, U, L, DOLOAD)                                                \
  {                                                                            \
    if (DOLOAD) { LDW(L, (ks) + 2); }                                          \
    constexpr int d_ = ((ks) & 1) * 16384 + (((ks) >> 1) / 3) * 1024 +         \
                       (((ks) >> 1) % 3) * 16;                                 \
    {                                                                          \
      i32x4 q0 = *(const i32x4*)(&lds[lb0 + d_]);                              \
      i32x4 q1 = *(const i32x4*)(&lds[lb1 + d_]);                              \
      i32x4 q2 = *(const i32x4*)(&lds[lb2 + d_]);                              \
      i32x4 q3 = *(const i32x4*)(&lds[lb3 + d_]);                              \
      __builtin_amdgcn_s_setprio(1);                                           \
      a0_0 = __builtin_amdgcn_mfma_i32_16x16x64_i8(U##0, q0, a0_0, 0, 0, 0);   \
      a1_0 = __builtin_amdgcn_mfma_i32_16x16x64_i8(U##1, q0, a1_0, 0, 0, 0);   \
      a0_1 = __builtin_amdgcn_mfma_i32_16x16x64_i8(U##0, q1, a0_1, 0, 0, 0);   \
      a1_1 = __builtin_amdgcn_mfma_i32_16x16x64_i8(U##1, q1, a1_1, 0, 0, 0);   \
      a0_2 = __builtin_amdgcn_mfma_i32_16x16x64_i8(U##0, q2, a0_2, 0, 0, 0);   \
      a1_2 = __builtin_amdgcn_mfma_i32_16x16x64_i8(U##1, q2, a1_2, 0, 0, 0);   \
      a0_3 = __builtin_amdgcn_mfma_i32_16x16x64_i8(U##0, q3, a0_3, 0, 0, 0);   \
      a1_3 = __builtin_amdgcn_mfma_i32_16x16x64_i8(U##1, q3, a1_3, 0, 0, 0);   \
      __builtin_amdgcn_s_setprio(0);                                           \
    }                                                                          \
    {                                                                          \
      i32x4 q4 = *(const i32x4*)(&lds[lb4 + d_]);                              \
      i32x4 q5 = *(const i32x4*)(&lds[lb5 + d_]);                              \
      i32x4 q6 = *(const i32x4*)(&lds[lb6 + d_]);                              \
      __builtin_amdgcn_s_setprio(1);                                           \
      a0_4 = __builtin_amdgcn_mfma_i32_16x16x64_i8(U##0, q4, a0_4, 0, 0, 0);   \
      a1_4 = __builtin_amdgcn_mfma_i32_16x16x64_i8(U##1, q4, a1_4, 0, 0, 0);   \
      a0_5 = __builtin_amdgcn_mfma_i32_16x16x64_i8(U##0, q5, a0_5, 0, 0, 0);   \
      a1_5 = __builtin_amdgcn_mfma_i32_16x16x64_i8(U##1, q5, a1_5, 0, 0, 0);   \
      a0_6 = __builtin_amdgcn_mfma_i32_16x16x64_i8(U##0, q6, a0_6, 0, 0, 0);   \
      a1_6 = __builtin_amdgcn_mfma_i32_16x16x64_i8(U##1, q6, a1_6, 0, 0, 0);   \
      __builtin_amdgcn_s_setprio(0);                                           \
    }                                                                          \
  }

  KSTEP(0,  wa, wc, 1)  KSTEP(1,  wb, wa, 1)  KSTEP(2,  wc, wb, 1)
  KSTEP(3,  wa, wc, 1)  KSTEP(4,  wb, wa, 1)  KSTEP(5,  wc, wb, 1)
  KSTEP(6,  wa, wc, 1)  KSTEP(7,  wb, wa, 1)  KSTEP(8,  wc, wb, 1)
  KSTEP(9,  wa, wc, 1)  KSTEP(10, wb, wa, 1)  KSTEP(11, wc, wb, 1)
  KSTEP(12, wa, wc, 1)  KSTEP(13, wb, wa, 1)  KSTEP(14, wc, wb, 1)
  KSTEP(15, wa, wc, 1)  KSTEP(16, wb, wa, 0)  KSTEP(17, wc, wb, 0)
#undef KSTEP
#undef LDW

  // ---- epilogue: C frag 16x16: px col = pxl, co row = c16*4 + j (+ m*16)
  float* obase = out + ((size_t)n * C_OUT + cq * 128) * PXROW + y0 * W_OUT;
  const float asf0 = asf_lds[pxl];
  const float asf1 = asf_lds[16 + pxl];
  const float asf2 = asf_lds[32 + pxl];
  const float asf3 = asf_lds[48 + pxl];
  const float asf4 = asf_lds[64 + pxl];
  const float asf5 = asf_lds[80 + pxl];
  const int j6 = 96 + pxl;
  const float asf6 = (j6 < 108) ? asf_lds[j6] : 0.0f;
#pragma unroll
  for (int m = 0; m < 2; ++m) {
#pragma unroll
    for (int j = 0; j < 4; ++j) {
      int co = w * 32 + m * 16 + c16 * 4 + j;   // co within 128-co block
      float bc = bconst[cq * 128 + co];
      float* o = obase + (size_t)co * PXROW;
      const i32x4& v0 = m ? a1_0 : a0_0;
      const i32x4& v1 = m ? a1_1 : a0_1;
      const i32x4& v2 = m ? a1_2 : a0_2;
      const i32x4& v3 = m ? a1_3 : a0_3;
      const i32x4& v4 = m ? a1_4 : a0_4;
      const i32x4& v5 = m ? a1_5 : a0_5;
      const i32x4& v6 = m ? a1_6 : a0_6;
      o[pxl]      = 1e-4f * (float)v0[j] + asf0 + bc;
      o[16 + pxl] = 1e-4f * (float)v1[j] + asf1 + bc;
      o[32 + pxl] = 1e-4f * (float)v2[j] + asf2 + bc;
      o[48 + pxl] = 1e-4f * (float)v3[j] + asf3 + bc;
      o[64 + pxl] = 1e-4f * (float)v4[j] + asf4 + bc;
      o[80 + pxl] = 1e-4f * (float)v5[j] + asf5 + bc;
      if (j6 < 108)
        o[j6] = 1e-4f * (float)v6[j] + asf6 + bc;
    }
  }
}

// ---------------- fallback (tiny ws): naive direct conv
__global__ void conv_naive(const int* __restrict__ in, const int* __restrict__ w,
                           const float* __restrict__ bias, float* __restrict__ out) {
  size_t idx = (size_t)blockIdx.x * 256 + threadIdx.x;
  size_t total = (size_t)N_B * C_OUT * H_OUT * W_OUT;
  if (idx >= total) return;
  int x = idx % W_OUT; size_t t = idx / W_OUT;
  int y = t % H_OUT; t /= H_OUT;
  int co = t % C_OUT; int n = (int)(t / C_OUT);
  int acc = 0;
  for (int ci = 0; ci < C_IN; ++ci) {
    const int* ib = in + (((size_t)n * C_IN + ci) * H_IN + y) * W_IN + x;
    const int* wb = w + (((size_t)co * C_IN + ci) * 3) * 3;
    for (int kh = 0; kh < 3; ++kh)
      for (int kw = 0; kw < 3; ++kw)
        acc += (ib[kh * W_IN + kw] - 7) * (wb[kh * 3 + kw] - 3);
  }
  float r = rintf(bias[co] / 0.0001f);
  r = fminf(fmaxf(r, -2147483648.0f), 2147483647.0f);
  out[idx] = (float)acc * (0.01f * 0.01f) + r * 0.0001f;
}

extern "C" void kernel_launch(void* const* d_in, const int* in_sizes, int n_in,
                              void* d_out, int out_size, void* d_ws, size_t ws_size,
                              hipStream_t stream) {
  const int*   in   = (const int*)d_in[0];
  const int*   w    = (const int*)d_in[1];
  const float* bias = (const float*)d_in[2];
  float*       out  = (float*)d_out;

  const size_t WQ_OFF = 0;                          // 294912
  const size_t IP_OFF = 294912;                     // 32*56*8192 = 14680064
  const size_t RS_OFF = IP_OFF + 14680064;          // 401408
  const size_t BC_OFF = RS_OFF + 401408;            // 1024
  const size_t NEED   = BC_OFF + 1024;              // ~15.4 MB

  if (ws_size >= NEED) {
    char* ws = (char*)d_ws;
    signed char* wq3  = (signed char*)(ws + WQ_OFF);
    signed char* ip2  = (signed char*)(ws + IP_OFF);
    int*         rs   = (int*)(ws + RS_OFF);
    float*       bc   = (float*)(ws + BC_OFF);

    prep<<<1920, 256, 0, stream>>>(in, w, bias, ip2, rs, wq3, bc);
    conv_mfma<<<1728, 256, 0, stream>>>(ip2, wq3, rs, bc, out);
  } else {
    size_t total = (size_t)N_B * C_OUT * H_OUT * W_OUT;
    conv_naive<<<(total + 255) / 256, 256, 0, stream>>>(in, w, bias, out);
  }
}

// Round 17
// 49.643 us; speedup vs baseline: 1.0119x; 1.0119x over previous
//
#include <hip/hip_runtime.h>
#include <hip/hip_bf16.h>

// Quantized int8 3x3 conv via implicit-im2col MFMA (mfma_i32_16x16x64_i8).
// out = 1e-4*dot + asumf[px] + bconst[co]
//
// Round-17 structure (R16 conv unchanged + conflict-free prep transpose):
//   - prep repack_in rewritten: w-major scratch t32[w][ci pad 132]
//       write: ds_write_b32, bank = (4*row + 16*hf + ci)%32 -> 2 lanes/bank FREE
//       read:  4x aligned ds_read_b128, lanes stride 528B -> all banks uniform
//     (old layout was 16-way on writes, 8-way on reads ~ 7us/CU serialized)
//   - conv: m2 x p7, A L2->regs triple-buffer, no loop barriers, XCD swizzle

#define N_B   32
#define C_IN  128
#define H_IN  56
#define W_IN  56
#define C_OUT 256
#define H_OUT 54
#define W_OUT 54
#define K_TOT 1152
#define NPX   (N_B * H_OUT * W_OUT)   // 93312
#define PXROW (H_OUT * W_OUT)         // 2916

using i32x4  = __attribute__((ext_vector_type(4))) int;

static __device__ __forceinline__ int dot4(int a, int b, int c) {
#if __has_builtin(__builtin_amdgcn_sdot4)
  return __builtin_amdgcn_sdot4(a, b, c, false);
#else
  signed char a0 = (signed char)a, a1 = (signed char)(a >> 8),
              a2 = (signed char)(a >> 16), a3 = (signed char)(a >> 24);
  signed char b0 = (signed char)b, b1 = (signed char)(b >> 8),
              b2 = (signed char)(b >> 16), b3 = (signed char)(b >> 24);
  return c + a0 * b0 + a1 * b1 + a2 * b2 + a3 * b3;
#endif
}

static __device__ __forceinline__ int pack4(int4 v) {
  return (v.x & 255) | ((v.y & 255) << 8) | ((v.z & 255) << 16) | ((v.w & 255) << 24);
}

__device__ __forceinline__ void gload16(const void* g, void* l) {
  __builtin_amdgcn_global_load_lds(
      (const __attribute__((address_space(1))) void*)g,
      (__attribute__((address_space(3))) void*)l, 16, 0, 0);
}

// ---------------- fused prep:
//   blocks [0,1792): repack_in  NCHW(int32) -> ip2[n][h][q8][w64][16B] + rs
//   blocks [1792,1920): repack_w (2 co per block) -> wq3 + bconst
__global__ void prep(const int* __restrict__ in, const int* __restrict__ wsrc,
                     const float* __restrict__ bias,
                     signed char* __restrict__ ip2, int* __restrict__ rs,
                     signed char* __restrict__ wq3, float* __restrict__ bconst) {
  const int bid = blockIdx.x, tid = threadIdx.x;
  __shared__ int t32[W_IN][132];     // ~29.6KB, w-major, ci padded to 132
  __shared__ int rsum[W_IN];

  if (bid < 1792) {
    const int h = bid % 56, n = bid / 56;
    if (tid < W_IN) rsum[tid] = 0;
    // ---- phase A: coalesced global read, conflict-free b32 LDS writes
    int ci = tid >> 1, hf = tid & 1;
    const int* s = in + ((size_t)n * C_IN + ci) * (H_IN * W_IN) + h * W_IN + hf * 28;
#pragma unroll
    for (int k = 0; k < 7; ++k) {
      int4 v = *(const int4*)(s + k * 4);
      int wr = hf * 28 + k * 4;
      t32[wr + 0][ci] = v.x;
      t32[wr + 1][ci] = v.y;
      t32[wr + 2][ci] = v.z;
      t32[wr + 3][ci] = v.w;
    }
    __syncthreads();

    // ---- phase B: b128 reads at bank floor, pack, coalesced int4 stores
    signed char* dst = ip2 + ((size_t)n * H_IN + h) * 8192;
    for (int u = tid; u < 448; u += 256) {
      int w = u % 56, c16 = u / 56;
      int4 q0 = *(const int4*)&t32[w][c16 * 16 + 0];
      int4 q1 = *(const int4*)&t32[w][c16 * 16 + 4];
      int4 q2 = *(const int4*)&t32[w][c16 * 16 + 8];
      int4 q3 = *(const int4*)&t32[w][c16 * 16 + 12];
      int b[4];
      b[0] = pack4(q0); b[1] = pack4(q1); b[2] = pack4(q2); b[3] = pack4(q3);
      int srow = 0;
      srow = dot4(b[0], 0x01010101, srow);
      srow = dot4(b[1], 0x01010101, srow);
      srow = dot4(b[2], 0x01010101, srow);
      srow = dot4(b[3], 0x01010101, srow);
      *(int4*)(dst + (size_t)c16 * 1024 + w * 16) = *(int4*)b;
      atomicAdd(&rsum[w], srow);
    }
    __syncthreads();
    if (tid < W_IN) rs[((size_t)n * H_IN + h) * W_IN + tid] = rsum[tid];
  } else {
    int* red = &t32[0][0];
    const int co = (bid - 1792) * 2 + (tid >> 7);
    const int ci = tid & 127;
    const int* wrow = wsrc + (size_t)co * K_TOT + (size_t)ci * 9;
    int s = 0;
    int kk = ci >> 5, hh = (ci >> 4) & 1, b = ci & 15;
    size_t base = (size_t)kk * 8192 + hh * 4096 + co * 16 + b;
#pragma unroll
    for (int t = 0; t < 9; ++t) {
      int v = wrow[t];
      s += v;
      wq3[(size_t)t * 32768 + base] = (signed char)v;
    }
    red[tid] = s;
    __syncthreads();
    for (int off = 64; off > 0; off >>= 1) {
      if (ci < off) red[tid] += red[tid + off];
      __syncthreads();
    }
    if (ci == 0) {
      int wsum = red[tid];
      float r = rintf(bias[co] / 0.0001f);                 // round half-even
      r = fminf(fmaxf(r, -2147483648.0f), 2147483647.0f);  // clamp to i32 range
      bconst[co] = 1e-4f * (float)(-7 * wsum + 24192) + r * 0.0001f;
    }
  }
}

__device__ __forceinline__ int mklb(int pf, int pxl, int c16) {
  int j = pf * 16 + pxl;
  int jc = j > 107 ? 107 : j;
  int dy = (jc >= 54) ? 1 : 0;
  return c16 * 4096 + dy * 1024 + (jc - dy * 54) * 16;
}

// ---------------- main MFMA conv (asum folded in)  [R16 body, unchanged]
__launch_bounds__(256, 4)
__global__ void conv_mfma(const signed char* __restrict__ ip2,
                          const signed char* __restrict__ wq3,
                          const int* __restrict__ rs,
                          const float* __restrict__ bconst,
                          float* __restrict__ out) {
  __shared__ signed char lds[32768];   // [plane i(8)=ci/16][row(4)][w(64)][16B]
  __shared__ float asf_lds[112];
  const int tid = threadIdx.x, w = tid >> 6, l = tid & 63;
  const int c16 = l >> 4, pxl = l & 15;

  // chunked XCD swizzle: 1728 = 8 xcd * 216
  const int b0 = blockIdx.x;
  const int wg = (b0 & 7) * 216 + (b0 >> 3);
  const int cq = wg & 1;               // co half 0..1
  const int nr = wg >> 1;              // n*27 + rp
  const int n  = nr / 27;
  const int rp = nr - n * 27;
  const int y0 = rp * 2;

  // ---- stage slab DENSE (4 input rows, 32KB)
  const signed char* ipn = ip2 + ((size_t)n * H_IN + y0) * 8192;
  {
    const int r = tid >> 6;
    const int off = (tid & 63) * 16;
    const signed char* src = ipn + (size_t)r * 8192 + off;
#pragma unroll
    for (int i = 0; i < 8; ++i)
      gload16(src + (size_t)i * 1024, &lds[i * 4096 + tid * 16]);
  }

  // ---- inline asum: asf_lds[j] = -3e-4 * sum of 3x3 rs window (L2-hot)
  if (tid < 108) {
    int dy = (tid >= 54) ? 1 : 0;
    int x  = tid - dy * 54;
    const int* rp_ = rs + ((size_t)n * H_IN + y0 + dy) * W_IN + x;
    int s = 0;
#pragma unroll
    for (int kh = 0; kh < 3; ++kh)
      s += rp_[kh * W_IN + 0] + rp_[kh * W_IN + 1] + rp_[kh * W_IN + 2];
    asf_lds[tid] = -3e-4f * (float)s;
  }

  // ---- per-lane B pixel bases: pf covers px j = pf*16 + pxl (112 px tile)
  const int lb0 = mklb(0, pxl, c16), lb1 = mklb(1, pxl, c16), lb2 = mklb(2, pxl, c16),
            lb3 = mklb(3, pxl, c16), lb4 = mklb(4, pxl, c16), lb5 = mklb(5, pxl, c16),
            lb6 = mklb(6, pxl, c16);

  // ---- A source: co = cq*128 + w*32 + m*16 + pxl, k-chunk c16
  const signed char* awq = wq3 + (size_t)c16 * 4096 +
                           (size_t)(cq * 128 + w * 32 + pxl) * 16;

  i32x4 a0_0 = {0,0,0,0}, a0_1 = {0,0,0,0}, a0_2 = {0,0,0,0}, a0_3 = {0,0,0,0},
        a0_4 = {0,0,0,0}, a0_5 = {0,0,0,0}, a0_6 = {0,0,0,0};
  i32x4 a1_0 = {0,0,0,0}, a1_1 = {0,0,0,0}, a1_2 = {0,0,0,0}, a1_3 = {0,0,0,0},
        a1_4 = {0,0,0,0}, a1_5 = {0,0,0,0}, a1_6 = {0,0,0,0};
  i32x4 wa0, wa1, wb0, wb1, wc0, wc1;

#define LDW(P, t)                                                              \
  P##0 = *(const i32x4*)(awq + (size_t)(t) * 16384);                           \
  P##1 = *(const i32x4*)(awq + (size_t)(t) * 16384 + 256);

  LDW(wa, 0);
  LDW(wb, 1);
  __syncthreads();   // slab + asf staged — the ONLY barrier

  // A triple buffer: kstep ks uses buf[ks%3], prefetches ks+2 into buf[(ks+2)%3]
#define KSTEP(ks, U, L, DOLOAD)                                                \
  {                                                                            \
    if (DOLOAD) { LDW(L, (ks) + 2); }                                          \
    constexpr int d_ = ((ks) & 1) * 16384 + (((ks) >> 1) / 3) * 1024 +         \
                       (((ks) >> 1) % 3) * 16;                                 \
    {                                                                          \
      i32x4 q0 = *(const i32x4*)(&lds[lb0 + d_]);                              \
      i32x4 q1 = *(const i32x4*)(&lds[lb1 + d_]);                              \
      i32x4 q2 = *(const i32x4*)(&lds[lb2 + d_]);                              \
      i32x4 q3 = *(const i32x4*)(&lds[lb3 + d_]);                              \
      __builtin_amdgcn_s_setprio(1);                                           \
      a0_0 = __builtin_amdgcn_mfma_i32_16x16x64_i8(U##0, q0, a0_0, 0, 0, 0);   \
      a1_0 = __builtin_amdgcn_mfma_i32_16x16x64_i8(U##1, q0, a1_0, 0, 0, 0);   \
      a0_1 = __builtin_amdgcn_mfma_i32_16x16x64_i8(U##0, q1, a0_1, 0, 0, 0);   \
      a1_1 = __builtin_amdgcn_mfma_i32_16x16x64_i8(U##1, q1, a1_1, 0, 0, 0);   \
      a0_2 = __builtin_amdgcn_mfma_i32_16x16x64_i8(U##0, q2, a0_2, 0, 0, 0);   \
      a1_2 = __builtin_amdgcn_mfma_i32_16x16x64_i8(U##1, q2, a1_2, 0, 0, 0);   \
      a0_3 = __builtin_amdgcn_mfma_i32_16x16x64_i8(U##0, q3, a0_3, 0, 0, 0);   \
      a1_3 = __builtin_amdgcn_mfma_i32_16x16x64_i8(U##1, q3, a1_3, 0, 0, 0);   \
      __builtin_amdgcn_s_setprio(0);                                           \
    }                                                                          \
    {                                                                          \
      i32x4 q4 = *(const i32x4*)(&lds[lb4 + d_]);                              \
      i32x4 q5 = *(const i32x4*)(&lds[lb5 + d_]);                              \
      i32x4 q6 = *(const i32x4*)(&lds[lb6 + d_]);                              \
      __builtin_amdgcn_s_setprio(1);                                           \
      a0_4 = __builtin_amdgcn_mfma_i32_16x16x64_i8(U##0, q4, a0_4, 0, 0, 0);   \
      a1_4 = __builtin_amdgcn_mfma_i32_16x16x64_i8(U##1, q4, a1_4, 0, 0, 0);   \
      a0_5 = __builtin_amdgcn_mfma_i32_16x16x64_i8(U##0, q5, a0_5, 0, 0, 0);   \
      a1_5 = __builtin_amdgcn_mfma_i32_16x16x64_i8(U##1, q5, a1_5, 0, 0, 0);   \
      a0_6 = __builtin_amdgcn_mfma_i32_16x16x64_i8(U##0, q6, a0_6, 0, 0, 0);   \
      a1_6 = __builtin_amdgcn_mfma_i32_16x16x64_i8(U##1, q6, a1_6, 0, 0, 0);   \
      __builtin_amdgcn_s_setprio(0);                                           \
    }                                                                          \
  }

  KSTEP(0,  wa, wc, 1)  KSTEP(1,  wb, wa, 1)  KSTEP(2,  wc, wb, 1)
  KSTEP(3,  wa, wc, 1)  KSTEP(4,  wb, wa, 1)  KSTEP(5,  wc, wb, 1)
  KSTEP(6,  wa, wc, 1)  KSTEP(7,  wb, wa, 1)  KSTEP(8,  wc, wb, 1)
  KSTEP(9,  wa, wc, 1)  KSTEP(10, wb, wa, 1)  KSTEP(11, wc, wb, 1)
  KSTEP(12, wa, wc, 1)  KSTEP(13, wb, wa, 1)  KSTEP(14, wc, wb, 1)
  KSTEP(15, wa, wc, 1)  KSTEP(16, wb, wa, 0)  KSTEP(17, wc, wb, 0)
#undef KSTEP
#undef LDW

  // ---- epilogue: C frag 16x16: px col = pxl, co row = c16*4 + j (+ m*16)
  float* obase = out + ((size_t)n * C_OUT + cq * 128) * PXROW + y0 * W_OUT;
  const float asf0 = asf_lds[pxl];
  const float asf1 = asf_lds[16 + pxl];
  const float asf2 = asf_lds[32 + pxl];
  const float asf3 = asf_lds[48 + pxl];
  const float asf4 = asf_lds[64 + pxl];
  const float asf5 = asf_lds[80 + pxl];
  const int j6 = 96 + pxl;
  const float asf6 = (j6 < 108) ? asf_lds[j6] : 0.0f;
#pragma unroll
  for (int m = 0; m < 2; ++m) {
#pragma unroll
    for (int j = 0; j < 4; ++j) {
      int co = w * 32 + m * 16 + c16 * 4 + j;   // co within 128-co block
      float bc = bconst[cq * 128 + co];
      float* o = obase + (size_t)co * PXROW;
      const i32x4& v0 = m ? a1_0 : a0_0;
      const i32x4& v1 = m ? a1_1 : a0_1;
      const i32x4& v2 = m ? a1_2 : a0_2;
      const i32x4& v3 = m ? a1_3 : a0_3;
      const i32x4& v4 = m ? a1_4 : a0_4;
      const i32x4& v5 = m ? a1_5 : a0_5;
      const i32x4& v6 = m ? a1_6 : a0_6;
      o[pxl]      = 1e-4f * (float)v0[j] + asf0 + bc;
      o[16 + pxl] = 1e-4f * (float)v1[j] + asf1 + bc;
      o[32 + pxl] = 1e-4f * (float)v2[j] + asf2 + bc;
      o[48 + pxl] = 1e-4f * (float)v3[j] + asf3 + bc;
      o[64 + pxl] = 1e-4f * (float)v4[j] + asf4 + bc;
      o[80 + pxl] = 1e-4f * (float)v5[j] + asf5 + bc;
      if (j6 < 108)
        o[j6] = 1e-4f * (float)v6[j] + asf6 + bc;
    }
  }
}

// ---------------- fallback (tiny ws): naive direct conv
__global__ void conv_naive(const int* __restrict__ in, const int* __restrict__ w,
                           const float* __restrict__ bias, float* __restrict__ out) {
  size_t idx = (size_t)blockIdx.x * 256 + threadIdx.x;
  size_t total = (size_t)N_B * C_OUT * H_OUT * W_OUT;
  if (idx >= total) return;
  int x = idx % W_OUT; size_t t = idx / W_OUT;
  int y = t % H_OUT; t /= H_OUT;
  int co = t % C_OUT; int n = (int)(t / C_OUT);
  int acc = 0;
  for (int ci = 0; ci < C_IN; ++ci) {
    const int* ib = in + (((size_t)n * C_IN + ci) * H_IN + y) * W_IN + x;
    const int* wb = w + (((size_t)co * C_IN + ci) * 3) * 3;
    for (int kh = 0; kh < 3; ++kh)
      for (int kw = 0; kw < 3; ++kw)
        acc += (ib[kh * W_IN + kw] - 7) * (wb[kh * 3 + kw] - 3);
  }
  float r = rintf(bias[co] / 0.0001f);
  r = fminf(fmaxf(r, -2147483648.0f), 2147483647.0f);
  out[idx] = (float)acc * (0.01f * 0.01f) + r * 0.0001f;
}

extern "C" void kernel_launch(void* const* d_in, const int* in_sizes, int n_in,
                              void* d_out, int out_size, void* d_ws, size_t ws_size,
                              hipStream_t stream) {
  const int*   in   = (const int*)d_in[0];
  const int*   w    = (const int*)d_in[1];
  const float* bias = (const float*)d_in[2];
  float*       out  = (float*)d_out;

  const size_t WQ_OFF = 0;                          // 294912
  const size_t IP_OFF = 294912;                     // 32*56*8192 = 14680064
  const size_t RS_OFF = IP_OFF + 14680064;          // 401408
  const size_t BC_OFF = RS_OFF + 401408;            // 1024
  const size_t NEED   = BC_OFF + 1024;              // ~15.4 MB

  if (ws_size >= NEED) {
    char* ws = (char*)d_ws;
    signed char* wq3  = (signed char*)(ws + WQ_OFF);
    signed char* ip2  = (signed char*)(ws + IP_OFF);
    int*         rs   = (int*)(ws + RS_OFF);
    float*       bc   = (float*)(ws + BC_OFF);

    prep<<<1920, 256, 0, stream>>>(in, w, bias, ip2, rs, wq3, bc);
    conv_mfma<<<1728, 256, 0, stream>>>(ip2, wq3, rs, bc, out);
  } else {
    size_t total = (size_t)N_B * C_OUT * H_OUT * W_OUT;
    conv_naive<<<(total + 255) / 256, 256, 0, stream>>>(in, w, bias, out);
  }
}

// Round 18
// 49.602 us; speedup vs baseline: 1.0128x; 1.0008x over previous
//
#include <hip/hip_runtime.h>
#include <hip/hip_bf16.h>

// Quantized int8 3x3 conv via implicit-im2col MFMA (mfma_i32_16x16x64_i8).
// out = 1e-4*dot + asumf[px] + bconst[co]
//
// Round-18 structure (R17 + in-register B prefetch pipeline):
//   - B fragments prefetched ONE HALF-STEP ahead into persistent regs
//     qa[4]/qb[3]: MFMA never waits on lgkm; LDS latency hides under the
//     wave's own MFMA cluster -> LDS pipe and matrix pipe finally overlap
//     (R12-R16 ran them serially: 17us + 14.5us back-to-back per CU)
//   - A back to double-buffer wa/wb (distance 1 == distance 2 measured)
//   - est ~119 VGPR < 128 cliff; all else identical to R17

#define N_B   32
#define C_IN  128
#define H_IN  56
#define W_IN  56
#define C_OUT 256
#define H_OUT 54
#define W_OUT 54
#define K_TOT 1152
#define NPX   (N_B * H_OUT * W_OUT)   // 93312
#define PXROW (H_OUT * W_OUT)         // 2916

using i32x4  = __attribute__((ext_vector_type(4))) int;

static __device__ __forceinline__ int dot4(int a, int b, int c) {
#if __has_builtin(__builtin_amdgcn_sdot4)
  return __builtin_amdgcn_sdot4(a, b, c, false);
#else
  signed char a0 = (signed char)a, a1 = (signed char)(a >> 8),
              a2 = (signed char)(a >> 16), a3 = (signed char)(a >> 24);
  signed char b0 = (signed char)b, b1 = (signed char)(b >> 8),
              b2 = (signed char)(b >> 16), b3 = (signed char)(b >> 24);
  return c + a0 * b0 + a1 * b1 + a2 * b2 + a3 * b3;
#endif
}

static __device__ __forceinline__ int pack4(int4 v) {
  return (v.x & 255) | ((v.y & 255) << 8) | ((v.z & 255) << 16) | ((v.w & 255) << 24);
}

__device__ __forceinline__ void gload16(const void* g, void* l) {
  __builtin_amdgcn_global_load_lds(
      (const __attribute__((address_space(1))) void*)g,
      (__attribute__((address_space(3))) void*)l, 16, 0, 0);
}

// ---------------- fused prep:
//   blocks [0,1792): repack_in  NCHW(int32) -> ip2[n][h][q8][w64][16B] + rs
//   blocks [1792,1920): repack_w (2 co per block) -> wq3 + bconst
__global__ void prep(const int* __restrict__ in, const int* __restrict__ wsrc,
                     const float* __restrict__ bias,
                     signed char* __restrict__ ip2, int* __restrict__ rs,
                     signed char* __restrict__ wq3, float* __restrict__ bconst) {
  const int bid = blockIdx.x, tid = threadIdx.x;
  __shared__ int t32[W_IN][132];     // ~29.6KB, w-major, ci padded to 132
  __shared__ int rsum[W_IN];

  if (bid < 1792) {
    const int h = bid % 56, n = bid / 56;
    if (tid < W_IN) rsum[tid] = 0;
    int ci = tid >> 1, hf = tid & 1;
    const int* s = in + ((size_t)n * C_IN + ci) * (H_IN * W_IN) + h * W_IN + hf * 28;
#pragma unroll
    for (int k = 0; k < 7; ++k) {
      int4 v = *(const int4*)(s + k * 4);
      int wr = hf * 28 + k * 4;
      t32[wr + 0][ci] = v.x;
      t32[wr + 1][ci] = v.y;
      t32[wr + 2][ci] = v.z;
      t32[wr + 3][ci] = v.w;
    }
    __syncthreads();

    signed char* dst = ip2 + ((size_t)n * H_IN + h) * 8192;
    for (int u = tid; u < 448; u += 256) {
      int w = u % 56, c16 = u / 56;
      int4 q0 = *(const int4*)&t32[w][c16 * 16 + 0];
      int4 q1 = *(const int4*)&t32[w][c16 * 16 + 4];
      int4 q2 = *(const int4*)&t32[w][c16 * 16 + 8];
      int4 q3 = *(const int4*)&t32[w][c16 * 16 + 12];
      int b[4];
      b[0] = pack4(q0); b[1] = pack4(q1); b[2] = pack4(q2); b[3] = pack4(q3);
      int srow = 0;
      srow = dot4(b[0], 0x01010101, srow);
      srow = dot4(b[1], 0x01010101, srow);
      srow = dot4(b[2], 0x01010101, srow);
      srow = dot4(b[3], 0x01010101, srow);
      *(int4*)(dst + (size_t)c16 * 1024 + w * 16) = *(int4*)b;
      atomicAdd(&rsum[w], srow);
    }
    __syncthreads();
    if (tid < W_IN) rs[((size_t)n * H_IN + h) * W_IN + tid] = rsum[tid];
  } else {
    int* red = &t32[0][0];
    const int co = (bid - 1792) * 2 + (tid >> 7);
    const int ci = tid & 127;
    const int* wrow = wsrc + (size_t)co * K_TOT + (size_t)ci * 9;
    int s = 0;
    int kk = ci >> 5, hh = (ci >> 4) & 1, b = ci & 15;
    size_t base = (size_t)kk * 8192 + hh * 4096 + co * 16 + b;
#pragma unroll
    for (int t = 0; t < 9; ++t) {
      int v = wrow[t];
      s += v;
      wq3[(size_t)t * 32768 + base] = (signed char)v;
    }
    red[tid] = s;
    __syncthreads();
    for (int off = 64; off > 0; off >>= 1) {
      if (ci < off) red[tid] += red[tid + off];
      __syncthreads();
    }
    if (ci == 0) {
      int wsum = red[tid];
      float r = rintf(bias[co] / 0.0001f);                 // round half-even
      r = fminf(fmaxf(r, -2147483648.0f), 2147483647.0f);  // clamp to i32 range
      bconst[co] = 1e-4f * (float)(-7 * wsum + 24192) + r * 0.0001f;
    }
  }
}

__device__ __forceinline__ int mklb(int pf, int pxl, int c16) {
  int j = pf * 16 + pxl;
  int jc = j > 107 ? 107 : j;
  int dy = (jc >= 54) ? 1 : 0;
  return c16 * 4096 + dy * 1024 + (jc - dy * 54) * 16;
}

// ---------------- main MFMA conv (asum folded in; B reg-pipelined)
__launch_bounds__(256, 4)
__global__ void conv_mfma(const signed char* __restrict__ ip2,
                          const signed char* __restrict__ wq3,
                          const int* __restrict__ rs,
                          const float* __restrict__ bconst,
                          float* __restrict__ out) {
  __shared__ signed char lds[32768];   // [plane i(8)=ci/16][row(4)][w(64)][16B]
  __shared__ float asf_lds[112];
  const int tid = threadIdx.x, w = tid >> 6, l = tid & 63;
  const int c16 = l >> 4, pxl = l & 15;

  // chunked XCD swizzle: 1728 = 8 xcd * 216
  const int b0 = blockIdx.x;
  const int wg = (b0 & 7) * 216 + (b0 >> 3);
  const int cq = wg & 1;               // co half 0..1
  const int nr = wg >> 1;              // n*27 + rp
  const int n  = nr / 27;
  const int rp = nr - n * 27;
  const int y0 = rp * 2;

  // ---- stage slab DENSE (4 input rows, 32KB)
  const signed char* ipn = ip2 + ((size_t)n * H_IN + y0) * 8192;
  {
    const int r = tid >> 6;
    const int off = (tid & 63) * 16;
    const signed char* src = ipn + (size_t)r * 8192 + off;
#pragma unroll
    for (int i = 0; i < 8; ++i)
      gload16(src + (size_t)i * 1024, &lds[i * 4096 + tid * 16]);
  }

  // ---- inline asum: asf_lds[j] = -3e-4 * sum of 3x3 rs window (L2-hot)
  if (tid < 108) {
    int dy = (tid >= 54) ? 1 : 0;
    int x  = tid - dy * 54;
    const int* rp_ = rs + ((size_t)n * H_IN + y0 + dy) * W_IN + x;
    int s = 0;
#pragma unroll
    for (int kh = 0; kh < 3; ++kh)
      s += rp_[kh * W_IN + 0] + rp_[kh * W_IN + 1] + rp_[kh * W_IN + 2];
    asf_lds[tid] = -3e-4f * (float)s;
  }

  // ---- per-lane B pixel bases: pf covers px j = pf*16 + pxl (112 px tile)
  const int lb0 = mklb(0, pxl, c16), lb1 = mklb(1, pxl, c16), lb2 = mklb(2, pxl, c16),
            lb3 = mklb(3, pxl, c16), lb4 = mklb(4, pxl, c16), lb5 = mklb(5, pxl, c16),
            lb6 = mklb(6, pxl, c16);

  // ---- A source: co = cq*128 + w*32 + m*16 + pxl, k-chunk c16
  const signed char* awq = wq3 + (size_t)c16 * 4096 +
                           (size_t)(cq * 128 + w * 32 + pxl) * 16;

  i32x4 a0_0 = {0,0,0,0}, a0_1 = {0,0,0,0}, a0_2 = {0,0,0,0}, a0_3 = {0,0,0,0},
        a0_4 = {0,0,0,0}, a0_5 = {0,0,0,0}, a0_6 = {0,0,0,0};
  i32x4 a1_0 = {0,0,0,0}, a1_1 = {0,0,0,0}, a1_2 = {0,0,0,0}, a1_3 = {0,0,0,0},
        a1_4 = {0,0,0,0}, a1_5 = {0,0,0,0}, a1_6 = {0,0,0,0};
  i32x4 wa0, wa1, wb0, wb1;          // A double buffer
  i32x4 qa0, qa1, qa2, qa3;          // B group-A prefetch regs (persistent)
  i32x4 qb0, qb1, qb2;               // B group-B prefetch regs (persistent)

#define LDW(P, t)                                                              \
  P##0 = *(const i32x4*)(awq + (size_t)(t) * 16384);                           \
  P##1 = *(const i32x4*)(awq + (size_t)(t) * 16384 + 256);

#define DOFF(ks) (((ks) & 1) * 16384 + (((ks) >> 1) / 3) * 1024 +              \
                  (((ks) >> 1) % 3) * 16)

#define RDQA(dd)                                                               \
  qa0 = *(const i32x4*)(&lds[lb0 + (dd)]);                                     \
  qa1 = *(const i32x4*)(&lds[lb1 + (dd)]);                                     \
  qa2 = *(const i32x4*)(&lds[lb2 + (dd)]);                                     \
  qa3 = *(const i32x4*)(&lds[lb3 + (dd)]);

#define RDQB(dd)                                                               \
  qb0 = *(const i32x4*)(&lds[lb4 + (dd)]);                                     \
  qb1 = *(const i32x4*)(&lds[lb5 + (dd)]);                                     \
  qb2 = *(const i32x4*)(&lds[lb6 + (dd)]);

#define MFA(U)                                                                 \
  __builtin_amdgcn_s_setprio(1);                                               \
  a0_0 = __builtin_amdgcn_mfma_i32_16x16x64_i8(U##0, qa0, a0_0, 0, 0, 0);      \
  a1_0 = __builtin_amdgcn_mfma_i32_16x16x64_i8(U##1, qa0, a1_0, 0, 0, 0);      \
  a0_1 = __builtin_amdgcn_mfma_i32_16x16x64_i8(U##0, qa1, a0_1, 0, 0, 0);      \
  a1_1 = __builtin_amdgcn_mfma_i32_16x16x64_i8(U##1, qa1, a1_1, 0, 0, 0);      \
  a0_2 = __builtin_amdgcn_mfma_i32_16x16x64_i8(U##0, qa2, a0_2, 0, 0, 0);      \
  a1_2 = __builtin_amdgcn_mfma_i32_16x16x64_i8(U##1, qa2, a1_2, 0, 0, 0);      \
  a0_3 = __builtin_amdgcn_mfma_i32_16x16x64_i8(U##0, qa3, a0_3, 0, 0, 0);      \
  a1_3 = __builtin_amdgcn_mfma_i32_16x16x64_i8(U##1, qa3, a1_3, 0, 0, 0);      \
  __builtin_amdgcn_s_setprio(0);

#define MFB(U)                                                                 \
  __builtin_amdgcn_s_setprio(1);                                               \
  a0_4 = __builtin_amdgcn_mfma_i32_16x16x64_i8(U##0, qb0, a0_4, 0, 0, 0);      \
  a1_4 = __builtin_amdgcn_mfma_i32_16x16x64_i8(U##1, qb0, a1_4, 0, 0, 0);      \
  a0_5 = __builtin_amdgcn_mfma_i32_16x16x64_i8(U##0, qb1, a0_5, 0, 0, 0);      \
  a1_5 = __builtin_amdgcn_mfma_i32_16x16x64_i8(U##1, qb1, a1_5, 0, 0, 0);      \
  a0_6 = __builtin_amdgcn_mfma_i32_16x16x64_i8(U##0, qb2, a0_6, 0, 0, 0);      \
  a1_6 = __builtin_amdgcn_mfma_i32_16x16x64_i8(U##1, qb2, a1_6, 0, 0, 0);      \
  __builtin_amdgcn_s_setprio(0);

  // kstep ks: uses A buf U (wa for even ks, wb odd), loads L = other, t=ks+1.
  // Pipeline: qb(cur) read hides under MFA; qa(next) read hides under MFB.
#define KSTEP(ks, U, L, DOLOAD)                                                \
  {                                                                            \
    if (DOLOAD) { LDW(L, (ks) + 1); }                                          \
    RDQB(DOFF(ks));                                                            \
    MFA(U);                                                                    \
    if ((ks) < 17) { RDQA(DOFF(((ks) + 1) % 18)); }                            \
    MFB(U);                                                                    \
  }

  LDW(wa, 0);
  __syncthreads();   // slab + asf staged — the ONLY barrier

  RDQA(DOFF(0));     // prime group-A regs for kstep 0

  KSTEP(0,  wa, wb, 1)  KSTEP(1,  wb, wa, 1)  KSTEP(2,  wa, wb, 1)
  KSTEP(3,  wb, wa, 1)  KSTEP(4,  wa, wb, 1)  KSTEP(5,  wb, wa, 1)
  KSTEP(6,  wa, wb, 1)  KSTEP(7,  wb, wa, 1)  KSTEP(8,  wa, wb, 1)
  KSTEP(9,  wb, wa, 1)  KSTEP(10, wa, wb, 1)  KSTEP(11, wb, wa, 1)
  KSTEP(12, wa, wb, 1)  KSTEP(13, wb, wa, 1)  KSTEP(14, wa, wb, 1)
  KSTEP(15, wb, wa, 1)  KSTEP(16, wa, wb, 1)  KSTEP(17, wb, wa, 0)
#undef KSTEP
#undef MFA
#undef MFB
#undef RDQA
#undef RDQB
#undef DOFF
#undef LDW

  // ---- epilogue: C frag 16x16: px col = pxl, co row = c16*4 + j (+ m*16)
  float* obase = out + ((size_t)n * C_OUT + cq * 128) * PXROW + y0 * W_OUT;
  const float asf0 = asf_lds[pxl];
  const float asf1 = asf_lds[16 + pxl];
  const float asf2 = asf_lds[32 + pxl];
  const float asf3 = asf_lds[48 + pxl];
  const float asf4 = asf_lds[64 + pxl];
  const float asf5 = asf_lds[80 + pxl];
  const int j6 = 96 + pxl;
  const float asf6 = (j6 < 108) ? asf_lds[j6] : 0.0f;
#pragma unroll
  for (int m = 0; m < 2; ++m) {
#pragma unroll
    for (int j = 0; j < 4; ++j) {
      int co = w * 32 + m * 16 + c16 * 4 + j;   // co within 128-co block
      float bc = bconst[cq * 128 + co];
      float* o = obase + (size_t)co * PXROW;
      const i32x4& v0 = m ? a1_0 : a0_0;
      const i32x4& v1 = m ? a1_1 : a0_1;
      const i32x4& v2 = m ? a1_2 : a0_2;
      const i32x4& v3 = m ? a1_3 : a0_3;
      const i32x4& v4 = m ? a1_4 : a0_4;
      const i32x4& v5 = m ? a1_5 : a0_5;
      const i32x4& v6 = m ? a1_6 : a0_6;
      o[pxl]      = 1e-4f * (float)v0[j] + asf0 + bc;
      o[16 + pxl] = 1e-4f * (float)v1[j] + asf1 + bc;
      o[32 + pxl] = 1e-4f * (float)v2[j] + asf2 + bc;
      o[48 + pxl] = 1e-4f * (float)v3[j] + asf3 + bc;
      o[64 + pxl] = 1e-4f * (float)v4[j] + asf4 + bc;
      o[80 + pxl] = 1e-4f * (float)v5[j] + asf5 + bc;
      if (j6 < 108)
        o[j6] = 1e-4f * (float)v6[j] + asf6 + bc;
    }
  }
}

// ---------------- fallback (tiny ws): naive direct conv
__global__ void conv_naive(const int* __restrict__ in, const int* __restrict__ w,
                           const float* __restrict__ bias, float* __restrict__ out) {
  size_t idx = (size_t)blockIdx.x * 256 + threadIdx.x;
  size_t total = (size_t)N_B * C_OUT * H_OUT * W_OUT;
  if (idx >= total) return;
  int x = idx % W_OUT; size_t t = idx / W_OUT;
  int y = t % H_OUT; t /= H_OUT;
  int co = t % C_OUT; int n = (int)(t / C_OUT);
  int acc = 0;
  for (int ci = 0; ci < C_IN; ++ci) {
    const int* ib = in + (((size_t)n * C_IN + ci) * H_IN + y) * W_IN + x;
    const int* wb = w + (((size_t)co * C_IN + ci) * 3) * 3;
    for (int kh = 0; kh < 3; ++kh)
      for (int kw = 0; kw < 3; ++kw)
        acc += (ib[kh * W_IN + kw] - 7) * (wb[kh * 3 + kw] - 3);
  }
  float r = rintf(bias[co] / 0.0001f);
  r = fminf(fmaxf(r, -2147483648.0f), 2147483647.0f);
  out[idx] = (float)acc * (0.01f * 0.01f) + r * 0.0001f;
}

extern "C" void kernel_launch(void* const* d_in, const int* in_sizes, int n_in,
                              void* d_out, int out_size, void* d_ws, size_t ws_size,
                              hipStream_t stream) {
  const int*   in   = (const int*)d_in[0];
  const int*   w    = (const int*)d_in[1];
  const float* bias = (const float*)d_in[2];
  float*       out  = (float*)d_out;

  const size_t WQ_OFF = 0;                          // 294912
  const size_t IP_OFF = 294912;                     // 32*56*8192 = 14680064
  const size_t RS_OFF = IP_OFF + 14680064;          // 401408
  const size_t BC_OFF = RS_OFF + 401408;            // 1024
  const size_t NEED   = BC_OFF + 1024;              // ~15.4 MB

  if (ws_size >= NEED) {
    char* ws = (char*)d_ws;
    signed char* wq3  = (signed char*)(ws + WQ_OFF);
    signed char* ip2  = (signed char*)(ws + IP_OFF);
    int*         rs   = (int*)(ws + RS_OFF);
    float*       bc   = (float*)(ws + BC_OFF);

    prep<<<1920, 256, 0, stream>>>(in, w, bias, ip2, rs, wq3, bc);
    conv_mfma<<<1728, 256, 0, stream>>>(ip2, wq3, rs, bc, out);
  } else {
    size_t total = (size_t)N_B * C_OUT * H_OUT * W_OUT;
    conv_naive<<<(total + 255) / 256, 256, 0, stream>>>(in, w, bias, out);
  }
}